// Round 7
// baseline (676.808 us; speedup 1.0000x reference)
//
#include <hip/hip_runtime.h>
#include <hip/hip_bf16.h>
#include <math.h>

// Problem constants
#define B_    32
#define DIM_  64
#define NP_   4
#define D_    1024
#define E_    768
#define VC_   32000
#define R_    2048          // B_*DIM_
#define KTOP  2
#define EPS_  1e-8f
#define NCB   250           // 32000 / 128 v-half-blocks (partial granularity)
#define NCAND 8

// Workspace layout (float offsets), ~319 MB total
#define T_OFF    ((size_t)0)
#define S_OFF    (T_OFF + (size_t)VC_ * D_)          // 32,768,000
#define INVW_OFF (S_OFF + (size_t)R_ * D_)           // 34,865,152
#define INVP_OFF (INVW_OFF + VC_)
#define WSQ_OFF  (INVP_OFF + R_)
#define PV_OFF   (WSQ_OFF + VC_)
#define PI_OFF   (PV_OFF + (size_t)R_ * NCB * 2)
#define SB_OFF   (PI_OFF + (size_t)R_ * NCB * 2)     // ushort region, R_*D_ ushorts
#define TB_OFF   (SB_OFF + (size_t)R_ * D_ / 2)      // ushort region, VC_*D_ ushorts
#define WH_OFF   (TB_OFF + (size_t)VC_ * D_ / 2)     // ushort region, D_*E_ ushorts
#define WL_OFF   (WH_OFF + (size_t)D_ * E_ / 2)
#define CAND_OFF (WL_OFF + (size_t)D_ * E_ / 2)
#define TIDX_OFF (CAND_OFF + (size_t)R_ * NCAND)
#define AH_OFF   (TIDX_OFF + (size_t)R_ * 2)         // ushort region, VC_*E_ ushorts (49.2 MB)
#define AL_OFF   (AH_OFF + (size_t)VC_ * E_ / 2)     // ushort region, VC_*E_ ushorts

#define NEG_INF (-3.4e38f)

typedef __bf16 bf16x8 __attribute__((ext_vector_type(8)));
typedef unsigned short u16x8 __attribute__((ext_vector_type(8)));
typedef float  f32x4  __attribute__((ext_vector_type(4)));

// global -> LDS direct copy, 16B per lane. LDS dest = wave-uniform base + lane*16.
__device__ __forceinline__ void async_ld16(const void* gptr, void* lptr) {
    __builtin_amdgcn_global_load_lds(
        (const __attribute__((address_space(1))) void*)(uintptr_t)gptr,
        (__attribute__((address_space(3))) void*)(unsigned)(uintptr_t)lptr,
        16, 0, 0);
}

__device__ __forceinline__ bool better(float v, int i, float bv, int bi) {
    return (v > bv) || (v == bv && i < bi);
}

// ---------------------------------------------------------------------------
// Kernel Z0: zero the wsq accumulator (ws is poisoned before every launch)
// ---------------------------------------------------------------------------
__global__ __launch_bounds__(256) void k_zero(float* __restrict__ wsq) {
    int i = blockIdx.x * 256 + threadIdx.x;
    if (i < VC_) wsq[i] = 0.f;
}

// ---------------------------------------------------------------------------
// Kernel S0: split fp32 array into bf16 hi/lo (RNE, native cvt).
// ---------------------------------------------------------------------------
__global__ __launch_bounds__(256) void k_split(const float* __restrict__ x,
                                               unsigned short* __restrict__ hi,
                                               unsigned short* __restrict__ lo) {
    int i = (blockIdx.x * 256 + threadIdx.x) * 4;   // grid sized exactly
    float4 v = *(const float4*)(x + i);
    ushort4 h, l;
    __bf16 b;
    b = (__bf16)v.x; h.x = __builtin_bit_cast(unsigned short, b); l.x = __builtin_bit_cast(unsigned short, (__bf16)(v.x - (float)b));
    b = (__bf16)v.y; h.y = __builtin_bit_cast(unsigned short, b); l.y = __builtin_bit_cast(unsigned short, (__bf16)(v.y - (float)b));
    b = (__bf16)v.z; h.z = __builtin_bit_cast(unsigned short, b); l.z = __builtin_bit_cast(unsigned short, (__bf16)(v.z - (float)b));
    b = (__bf16)v.w; h.w = __builtin_bit_cast(unsigned short, b); l.w = __builtin_bit_cast(unsigned short, (__bf16)(v.w - (float)b));
    *(ushort4*)(hi + i) = h;
    *(ushort4*)(lo + i) = l;
}

// ---------------------------------------------------------------------------
// Kernel A: s[r,d] = sum_np P[r,np,d]; sb = bf16(s); invp[r] = 1/max(||P_r||,eps)
// ---------------------------------------------------------------------------
__global__ __launch_bounds__(256) void k_sum_pnorm(const float* __restrict__ P,
                                                   float* __restrict__ s,
                                                   unsigned short* __restrict__ sb,
                                                   float* __restrict__ invp) {
    int r = blockIdx.x;
    int t = threadIdx.x;
    const float* base = P + (size_t)r * NP_ * D_;
    float4 acc = make_float4(0.f, 0.f, 0.f, 0.f);
    float sq = 0.f;
#pragma unroll
    for (int np = 0; np < NP_; ++np) {
        float4 v = *(const float4*)(base + (size_t)np * D_ + t * 4);
        acc.x += v.x; acc.y += v.y; acc.z += v.z; acc.w += v.w;
        sq += v.x * v.x + v.y * v.y + v.z * v.z + v.w * v.w;
    }
    *(float4*)(s + (size_t)r * D_ + t * 4) = acc;
    ushort4 o;
    __bf16 b;
    b = (__bf16)acc.x; o.x = __builtin_bit_cast(unsigned short, b);
    b = (__bf16)acc.y; o.y = __builtin_bit_cast(unsigned short, b);
    b = (__bf16)acc.z; o.z = __builtin_bit_cast(unsigned short, b);
    b = (__bf16)acc.w; o.w = __builtin_bit_cast(unsigned short, b);
    *(ushort4*)(sb + (size_t)r * D_ + t * 4) = o;

    __shared__ float red[256];
    red[t] = sq;
    __syncthreads();
    for (int off = 128; off > 0; off >>= 1) {
        if (t < off) red[t] += red[t + off];
        __syncthreads();
    }
    if (t == 0) invp[r] = 1.0f / fmaxf(sqrtf(red[0]), EPS_);
}

// ---------------------------------------------------------------------------
// Kernel B: split-bf16 MFMA GEMM, v6 — 256(v) x 128(d) tile, 8 waves (512 thr),
// BK=32, 3-buffer circular LDS pipeline, DEPTH-2 prefetch with vmcnt(12)
// (6 loads/stage; 2 tiles in flight spanning 2 barrier pairs — HBM latency
// covered; the wait is non-blocking in steady state).
//   T[v,d] = dot(few[v,:], we[d,:]) + bias[v]  via  Ah*Bh + Al*Bh + Ah*Bl
// Buffer safety: at iter kt we stage buf (kt+2)%3, last read in iter kt-1
// whose closing barrier precedes the issue. Dummy tail stages keep vmcnt
// invariant. Slot-rotation de-conflict; bijective XCD swizzle (1000=125x8).
// Wave grid 4(v) x 2(d); per-wave output 64v x 64d. LDS 144 KB, 1 block/CU.
// K-accumulation order unchanged vs v4 -> bit-identical T.
// ---------------------------------------------------------------------------
__global__ __launch_bounds__(512) void k_gemm_T_mfma(const unsigned short* __restrict__ Ahg, // few hi [VC,E]
                                                     const unsigned short* __restrict__ Alg, // few lo [VC,E]
                                                     const unsigned short* __restrict__ Bhg, // weh [D,E]
                                                     const unsigned short* __restrict__ Blg, // wel [D,E]
                                                     const float* __restrict__ bias,
                                                     float* __restrict__ T,
                                                     unsigned short* __restrict__ Tb,
                                                     float* __restrict__ wsq) {
    __shared__ __align__(16) unsigned short Ash[3][256 * 32];  // 3 x 16 KB
    __shared__ __align__(16) unsigned short Asl[3][256 * 32];  // 3 x 16 KB
    __shared__ __align__(16) unsigned short Bsh[3][128 * 32];  // 3 x  8 KB
    __shared__ __align__(16) unsigned short Bsl[3][128 * 32];  // 3 x  8 KB

    int tid = threadIdx.x;
    int wid = tid >> 6, lane = tid & 63;
    int quad = lane >> 4, l15 = lane & 15;
    int wm = wid >> 1, wn = wid & 1;       // 4 x 2 wave grid
    // Bijective XCD swizzle: nwg=1000, 125/XCD-chunk, v-major.
    int id  = blockIdx.x;
    int swz = (id & 7) * 125 + (id >> 3);
    int v0 = (swz >> 3) * 256;     // 125 v-panels
    int d0 = (swz & 7) * 128;      // 8 d-blocks per panel

    f32x4 acc[4][4];
#pragma unroll
    for (int i = 0; i < 4; ++i)
#pragma unroll
        for (int j = 0; j < 4; ++j) acc[i][j] = f32x4{0.f, 0.f, 0.f, 0.f};

    int r_lane = lane >> 2;            // staging row within 16-row group
    int slot   = lane & 3;             // physical 16B slot this lane writes

    // LDS physical (row, p) holds logical slot (p - (row>>1))&3 (bank
    // de-conflict); staged by pre-rotating the global source column.
#define STAGE_T(buf, kk)                                                           \
    {                                                                              \
_Pragma("unroll")                                                                  \
        for (int j = 0; j < 2; ++j) {                                              \
            int rowt = j * 128 + wid * 16 + r_lane;                                \
            int ss = (slot - (rowt >> 1)) & 3;                                     \
            async_ld16(Ahg + (size_t)(v0 + rowt) * E_ + (kk) + ss * 8,             \
                       (void*)(Ash[buf] + (j * 128 + wid * 16) * 32));             \
            async_ld16(Alg + (size_t)(v0 + rowt) * E_ + (kk) + ss * 8,             \
                       (void*)(Asl[buf] + (j * 128 + wid * 16) * 32));             \
        }                                                                          \
        {                                                                          \
            int rowb = wid * 16 + r_lane;                                          \
            int ssb = (slot - (rowb >> 1)) & 3;                                    \
            async_ld16(Bhg + (size_t)(d0 + rowb) * E_ + (kk) + ssb * 8,            \
                       (void*)(Bsh[buf] + (wid * 16) * 32));                       \
            async_ld16(Blg + (size_t)(d0 + rowb) * E_ + (kk) + ssb * 8,            \
                       (void*)(Bsl[buf] + (wid * 16) * 32));                       \
        }                                                                          \
    }

    // Prologue: 2 tiles in flight (12 loads/thread)
    STAGE_T(0, 0);
    STAGE_T(1, 32);

    const int NT = E_ / 32;            // 24 K-tiles
    int cur = 0;
    for (int kt = 0; kt < NT; ++kt) {
        int kn = (kt + 2 < NT) ? (kt + 2) * 32 : kt * 32;  // dummy tail re-stage
        int nb = cur + 2; if (nb >= 3) nb -= 3;
        STAGE_T(nb, kn);               // 6 more loads -> <=18 outstanding

        asm volatile("s_waitcnt vmcnt(12)" ::: "memory");   // tile kt landed
        __builtin_amdgcn_s_barrier();                       // buf[cur] ready
        asm volatile("" ::: "memory");

        bf16x8 fbh[4], fbl[4];
#pragma unroll
        for (int nt = 0; nt < 4; ++nt) {
            int row = wn * 64 + nt * 16 + l15;
            int ps = (quad + (row >> 1)) & 3;
            int off = row * 32 + ps * 8;
            fbh[nt] = *(const bf16x8*)(Bsh[cur] + off);
            fbl[nt] = *(const bf16x8*)(Bsl[cur] + off);
        }
        __builtin_amdgcn_s_setprio(1);
#pragma unroll
        for (int mt = 0; mt < 4; ++mt) {
            int row = wm * 64 + mt * 16 + l15;
            int ps = (quad + (row >> 1)) & 3;
            int off = row * 32 + ps * 8;
            bf16x8 fah = *(const bf16x8*)(Ash[cur] + off);
            bf16x8 fal = *(const bf16x8*)(Asl[cur] + off);
#pragma unroll
            for (int nt = 0; nt < 4; ++nt) {
                acc[mt][nt] = __builtin_amdgcn_mfma_f32_16x16x32_bf16(fah, fbh[nt], acc[mt][nt], 0, 0, 0);
                acc[mt][nt] = __builtin_amdgcn_mfma_f32_16x16x32_bf16(fal, fbh[nt], acc[mt][nt], 0, 0, 0);
                acc[mt][nt] = __builtin_amdgcn_mfma_f32_16x16x32_bf16(fah, fbl[nt], acc[mt][nt], 0, 0, 0);
            }
        }
        __builtin_amdgcn_s_setprio(0);

        __builtin_amdgcn_sched_barrier(0);   // keep reads+MFMA before barrier#2
        __builtin_amdgcn_s_barrier();        // all waves done reading buf[cur]
        asm volatile("" ::: "memory");
        cur = (cur == 2) ? 0 : cur + 1;
    }
#undef STAGE_T

    // Epilogue: T fp32, Tb bf16, row-sumsq partials -> wsq atomics
    float sq[4][4] = {};
#pragma unroll
    for (int mt = 0; mt < 4; ++mt) {
        int vbase = v0 + wm * 64 + mt * 16 + quad * 4;
        float bv[4];
#pragma unroll
        for (int rg = 0; rg < 4; ++rg) bv[rg] = bias[vbase + rg];
#pragma unroll
        for (int nt = 0; nt < 4; ++nt) {
            int d = d0 + wn * 64 + nt * 16 + l15;
#pragma unroll
            for (int rg = 0; rg < 4; ++rg) {
                float val = acc[mt][nt][rg] + bv[rg];
                T[(size_t)(vbase + rg) * D_ + d] = val;
                __bf16 vb = (__bf16)val;
                Tb[(size_t)(vbase + rg) * D_ + d] = __builtin_bit_cast(unsigned short, vb);
                sq[mt][rg] += val * val;
            }
        }
    }
#pragma unroll
    for (int mt = 0; mt < 4; ++mt)
#pragma unroll
        for (int rg = 0; rg < 4; ++rg) {
            float p = sq[mt][rg];
            p += __shfl_xor(p, 1); p += __shfl_xor(p, 2);
            p += __shfl_xor(p, 4); p += __shfl_xor(p, 8);
            if (l15 == 0) atomicAdd(&wsq[v0 + wm * 64 + mt * 16 + quad * 4 + rg], p);
        }
}

// ---------------------------------------------------------------------------
// Kernel W: invw[v] = 1 / max(2*sqrt(wsq[v]), eps)
// ---------------------------------------------------------------------------
__global__ __launch_bounds__(256) void k_invw(const float* __restrict__ wsq,
                                              float* __restrict__ invw) {
    int v = blockIdx.x * 256 + threadIdx.x;
    if (v < VC_) invw[v] = 1.0f / fmaxf(2.0f * sqrtf(wsq[v]), EPS_);
}

// ---------------------------------------------------------------------------
// Kernel C: bf16 MFMA candidate GEMM — 256x256 tile, 8 waves (512 thr),
// BK=32, 4-buffer circular LDS pipeline, depth-3 prefetch, vmcnt(12).
// (R6 form — measured 193.7 µs, BANK_CONFLICT 0, FETCH ~ideal.)
// ---------------------------------------------------------------------------
__global__ __launch_bounds__(512) void k_scores_mfma(const unsigned short* __restrict__ Tb,
                                                     const unsigned short* __restrict__ sb,
                                                     const float* __restrict__ invw,
                                                     float* __restrict__ pval,
                                                     int* __restrict__ pidx) {
    __shared__ __align__(16) unsigned short As[4][256 * 32];  // 4 x 16 KB  [v-row][k]
    __shared__ __align__(16) unsigned short Bs[4][256 * 32];  // 4 x 16 KB  [r-row][k]

    int tid = threadIdx.x;
    int wid = tid >> 6, lane = tid & 63;
    int quad = lane >> 4, l15 = lane & 15;
    int wm = wid >> 2, wn = wid & 3;       // 2 x 4 wave grid
    // T1: nwg=1000, 125/XCD-chunk, v-major (8 r-blocks of a panel on one XCD).
    int id   = blockIdx.x;
    int swz  = (id & 7) * 125 + (id >> 3);
    int vblk = swz >> 3;               // 0..124  (256-v panel)
    int rblk = swz & 7;                // 0..7    (256-r block)
    int v0 = vblk * 256;
    int r0 = rblk * 256;

    f32x4 acc[8][4];
#pragma unroll
    for (int i = 0; i < 8; ++i)
#pragma unroll
        for (int j = 0; j < 4; ++j) acc[i][j] = f32x4{0.f, 0.f, 0.f, 0.f};

    int r_lane = lane >> 2;            // staging row within 16-row group
    int slot   = lane & 3;             // physical 16B slot this lane writes

    // LDS physical (row, p) holds logical slot (p - (row>>1))&3 (bank
    // de-conflict); staged by pre-rotating the global source column.
#define STAGE_SC(buf, kk)                                                          \
    {                                                                              \
_Pragma("unroll")                                                                  \
        for (int j = 0; j < 2; ++j) {                                              \
            int rowt = j * 128 + wid * 16 + r_lane;                                \
            int ss = (slot - (rowt >> 1)) & 3;                                     \
            async_ld16(Tb + (size_t)(v0 + rowt) * D_ + (kk) + ss * 8,              \
                       (void*)(As[buf] + (j * 128 + wid * 16) * 32));              \
            async_ld16(sb + (size_t)(r0 + rowt) * D_ + (kk) + ss * 8,              \
                       (void*)(Bs[buf] + (j * 128 + wid * 16) * 32));              \
        }                                                                          \
    }

    // Prologue: 3 tiles in flight (12 loads/thread)
    STAGE_SC(0, 0);
    STAGE_SC(1, 32);
    STAGE_SC(2, 64);

    const int NT = D_ / 32;            // 32 K-tiles
    for (int kt = 0; kt < NT; ++kt) {
        int cur = kt & 3;
        int kn  = (kt + 3 < NT) ? (kt + 3) * 32 : kt * 32;  // dummy tail re-stage
        STAGE_SC((kt + 3) & 3, kn);    // 4 more loads -> <=16 outstanding

        asm volatile("s_waitcnt vmcnt(12)" ::: "memory");   // tile kt landed
        __builtin_amdgcn_s_barrier();                       // buf[cur] ready
        asm volatile("" ::: "memory");

        bf16x8 bfr[4];
#pragma unroll
        for (int nt = 0; nt < 4; ++nt) {
            int row = wn * 64 + nt * 16 + l15;
            int ps = (quad + (row >> 1)) & 3;
            bfr[nt] = *(const bf16x8*)(Bs[cur] + row * 32 + ps * 8);
        }
        __builtin_amdgcn_s_setprio(1);
#pragma unroll
        for (int mt = 0; mt < 8; ++mt) {
            int row = wm * 128 + mt * 16 + l15;
            int ps = (quad + (row >> 1)) & 3;
            bf16x8 af = *(const bf16x8*)(As[cur] + row * 32 + ps * 8);
#pragma unroll
            for (int nt = 0; nt < 4; ++nt)
                acc[mt][nt] = __builtin_amdgcn_mfma_f32_16x16x32_bf16(af, bfr[nt], acc[mt][nt], 0, 0, 0);
        }
        __builtin_amdgcn_s_setprio(0);

        __builtin_amdgcn_sched_barrier(0);   // keep reads+MFMA before barrier#2
        __builtin_amdgcn_s_barrier();        // all waves done reading buf[cur]
        asm volatile("" ::: "memory");
    }
#undef STAGE_SC

    // Epilogue: scale by invw[v]; per r, top-2 over this wave's 128 v's.
    // Each (wm) half-panel is its own partial block (NCB=250 layout kept).
    float iw[8][4];
#pragma unroll
    for (int mt = 0; mt < 8; ++mt)
#pragma unroll
        for (int rg = 0; rg < 4; ++rg)
            iw[mt][rg] = invw[v0 + wm * 128 + mt * 16 + quad * 4 + rg];

#pragma unroll
    for (int nt = 0; nt < 4; ++nt) {
        float b1 = NEG_INF, b2 = NEG_INF;
        int i1 = 0x7fffffff, i2 = 0x7fffffff;
#pragma unroll
        for (int mt = 0; mt < 8; ++mt)
#pragma unroll
            for (int rg = 0; rg < 4; ++rg) {
                float val = acc[mt][nt][rg] * iw[mt][rg];
                int v = v0 + wm * 128 + mt * 16 + quad * 4 + rg;
                if (better(val, v, b1, i1)) { b2 = b1; i2 = i1; b1 = val; i1 = v; }
                else if (better(val, v, b2, i2)) { b2 = val; i2 = v; }
            }
#pragma unroll
        for (int off = 16; off <= 32; off <<= 1) {
            float o1 = __shfl_xor(b1, off), o2 = __shfl_xor(b2, off);
            int  oi1 = __shfl_xor(i1, off), oi2 = __shfl_xor(i2, off);
            if (better(o1, oi1, b1, i1)) {
                if (better(b1, i1, o2, oi2)) { b2 = b1; i2 = i1; } else { b2 = o2; i2 = oi2; }
                b1 = o1; i1 = oi1;
            } else if (better(o1, oi1, b2, i2)) { b2 = o1; i2 = oi1; }
        }
        if (quad == 0) {
            int rl = wn * 64 + nt * 16 + l15;
            size_t off = ((size_t)(r0 + rl) * NCB + vblk * 2 + wm) * 2;
            pval[off] = b1;     pidx[off] = i1;
            pval[off + 1] = b2; pidx[off + 1] = i2;
        }
    }
}

// ---------------------------------------------------------------------------
// Kernel D: top-8 candidates per row from the 500 partials (approx ranking)
// ---------------------------------------------------------------------------
__global__ __launch_bounds__(256) void k_topk8(const float* __restrict__ pval,
                                               const int* __restrict__ pidx,
                                               int* __restrict__ cands) {
    int r = blockIdx.x, t = threadIdx.x;
    __shared__ float v[512];
    __shared__ int  id[512];
    for (int c = t; c < 512; c += 256) {
        if (c < NCB * 2) { v[c] = pval[(size_t)r * NCB * 2 + c]; id[c] = pidx[(size_t)r * NCB * 2 + c]; }
        else             { v[c] = NEG_INF; id[c] = 0x7fffffff; }
    }
    __syncthreads();
    if (t == 0) {
        float bv[NCAND]; int bi[NCAND];
#pragma unroll
        for (int j = 0; j < NCAND; ++j) { bv[j] = NEG_INF; bi[j] = 0x7fffffff; }
        for (int c = 0; c < NCB * 2; ++c) {
            float x = v[c]; int xi = id[c];
            if (better(x, xi, bv[NCAND - 1], bi[NCAND - 1])) {
                int j = NCAND - 1;
                while (j > 0 && better(x, xi, bv[j - 1], bi[j - 1])) {
                    bv[j] = bv[j - 1]; bi[j] = bi[j - 1]; --j;
                }
                bv[j] = x; bi[j] = xi;
            }
        }
#pragma unroll
        for (int j = 0; j < NCAND; ++j) cands[r * NCAND + j] = bi[j];
    }
}

// ---------------------------------------------------------------------------
// Kernel E: exact fp32 rescore of 8 candidates/row -> final top-2 + values
// ---------------------------------------------------------------------------
__global__ __launch_bounds__(256) void k_rescore(const float* __restrict__ s,
                                                 const float* __restrict__ T,
                                                 const int* __restrict__ cands,
                                                 const float* __restrict__ invw,
                                                 const float* __restrict__ invp,
                                                 float* __restrict__ outv,
                                                 int* __restrict__ tidx) {
    int r = blockIdx.x, t = threadIdx.x;
    int cg = t >> 5, l32 = t & 31;          // 8 groups of 32 lanes
    int c = cands[r * NCAND + cg];
    const float* Trow = T + (size_t)c * D_;
    const float* srow = s + (size_t)r * D_;
    float p = 0.f;
#pragma unroll
    for (int j = 0; j < 8; ++j) {
        int e = (j * 32 + l32) * 4;
        float4 a = *(const float4*)(srow + e);
        float4 b = *(const float4*)(Trow + e);
        p += a.x * b.x + a.y * b.y + a.z * b.z + a.w * b.w;
    }
#pragma unroll
    for (int off = 16; off >= 1; off >>= 1) p += __shfl_xor(p, off);  // stays in 32-group
    __shared__ float sc[NCAND];
    if (l32 == 0) sc[cg] = p;
    __syncthreads();
    if (t == 0) {
        float ip = invp[r];
        float b1 = NEG_INF, b2 = NEG_INF;
        int i1 = 0x7fffffff, i2 = 0x7fffffff;
#pragma unroll
        for (int j = 0; j < NCAND; ++j) {
            int ci = cands[r * NCAND + j];
            float val = sc[j] * invw[ci] * ip;
            if (better(val, ci, b1, i1)) { b2 = b1; i2 = i1; b1 = val; i1 = ci; }
            else if (better(val, ci, b2, i2)) { b2 = val; i2 = ci; }
        }
        outv[(size_t)r * 2 + 0] = b1;
        outv[(size_t)r * 2 + 1] = b2;
        tidx[r * 2 + 0] = i1;
        tidx[r * 2 + 1] = i2;
    }
}

// ---------------------------------------------------------------------------
// Kernel F: Z[r, 0:2, :] = T[idx], Z[r, 2:6, :] = P[r, :, :]
// ---------------------------------------------------------------------------
__global__ __launch_bounds__(256) void k_writeZ(const float* __restrict__ P,
                                                const float* __restrict__ T,
                                                const int* __restrict__ tidx,
                                                float* __restrict__ out) {
    int blk = blockIdx.x;  // r*6 + j
    int r = blk / 6, j = blk - r * 6;
    const float* src;
    if (j < KTOP) src = T + (size_t)tidx[r * 2 + j] * D_;
    else          src = P + ((size_t)r * NP_ + (j - KTOP)) * D_;
    float4 v = *(const float4*)(src + threadIdx.x * 4);
    *(float4*)(out + ((size_t)r * 6 + j) * D_ + threadIdx.x * 4) = v;
}

// ---------------------------------------------------------------------------
extern "C" void kernel_launch(void* const* d_in, const int* in_sizes, int n_in,
                              void* d_out, int out_size, void* d_ws, size_t ws_size,
                              hipStream_t stream) {
    const float* P   = (const float*)d_in[0];  // [32,64,4,1024]
    const float* we  = (const float*)d_in[1];  // [1024,768]
    const float* few = (const float*)d_in[2];  // [32000,768]
    const float* feb = (const float*)d_in[3];  // [32000]
    float* out = (float*)d_out;                // Z (12,582,912) then values (4096)
    float* ws  = (float*)d_ws;

    float* T    = ws + T_OFF;
    float* s    = ws + S_OFF;
    float* invw = ws + INVW_OFF;
    float* invp = ws + INVP_OFF;
    float* wsq  = ws + WSQ_OFF;
    float* pval = ws + PV_OFF;
    int*   pidx = (int*)(ws + PI_OFF);
    unsigned short* sb  = (unsigned short*)(ws + SB_OFF);
    unsigned short* Tb  = (unsigned short*)(ws + TB_OFF);
    unsigned short* weh = (unsigned short*)(ws + WH_OFF);
    unsigned short* wel = (unsigned short*)(ws + WL_OFF);
    int*   cands = (int*)(ws + CAND_OFF);
    int*   tidx  = (int*)(ws + TIDX_OFF);
    unsigned short* fewh = (unsigned short*)(ws + AH_OFF);
    unsigned short* fewl = (unsigned short*)(ws + AL_OFF);
    float* outv = out + (size_t)R_ * 6 * D_;

    k_zero<<<(VC_ + 255) / 256, 256, 0, stream>>>(wsq);
    k_split<<<(D_ * E_) / 1024, 256, 0, stream>>>(we, weh, wel);
    k_split<<<((size_t)VC_ * E_) / 1024, 256, 0, stream>>>(few, fewh, fewl);
    k_sum_pnorm<<<R_, 256, 0, stream>>>(P, s, sb, invp);
    k_gemm_T_mfma<<<1000, 512, 0, stream>>>(fewh, fewl, weh, wel, feb, T, Tb, wsq);
    k_invw<<<(VC_ + 255) / 256, 256, 0, stream>>>(wsq, invw);
    k_scores_mfma<<<1000, 512, 0, stream>>>(Tb, sb, invw, pval, pidx);
    k_topk8<<<R_, 256, 0, stream>>>(pval, pidx, cands);
    k_rescore<<<R_, 256, 0, stream>>>(s, T, cands, invw, invp, outv, tidx);
    k_writeZ<<<R_ * 6, 256, 0, stream>>>(P, T, tidx, out);
}

// Round 8
// 653.358 us; speedup vs baseline: 1.0359x; 1.0359x over previous
//
#include <hip/hip_runtime.h>
#include <hip/hip_bf16.h>
#include <math.h>

// Problem constants
#define B_    32
#define DIM_  64
#define NP_   4
#define D_    1024
#define E_    768
#define VC_   32000
#define R_    2048          // B_*DIM_
#define KTOP  2
#define EPS_  1e-8f
#define NCB   250           // 32000 / 128 v-half-blocks (partial granularity)
#define NCAND 8

// Workspace layout (float offsets). T fp32 region repurposed: TL (bf16 lo of T)
// lives in its first half (VC_*D_ ushorts = 16.384M floats < 32.768M floats).
#define T_OFF    ((size_t)0)
#define TL_OFF   T_OFF                               // ushort region, VC_*D_ ushorts
#define S_OFF    (T_OFF + (size_t)VC_ * D_)          // 32,768,000
#define INVW_OFF (S_OFF + (size_t)R_ * D_)           // 34,865,152
#define INVP_OFF (INVW_OFF + VC_)
#define WSQ_OFF  (INVP_OFF + R_)
#define PV_OFF   (WSQ_OFF + VC_)
#define PI_OFF   (PV_OFF + (size_t)R_ * NCB * 2)
#define SB_OFF   (PI_OFF + (size_t)R_ * NCB * 2)     // ushort region, R_*D_ ushorts
#define TB_OFF   (SB_OFF + (size_t)R_ * D_ / 2)      // ushort region, VC_*D_ ushorts (T hi)
#define WH_OFF   (TB_OFF + (size_t)VC_ * D_ / 2)     // ushort region, D_*E_ ushorts
#define WL_OFF   (WH_OFF + (size_t)D_ * E_ / 2)
#define CAND_OFF (WL_OFF + (size_t)D_ * E_ / 2)
#define TIDX_OFF (CAND_OFF + (size_t)R_ * NCAND)
#define AH_OFF   (TIDX_OFF + (size_t)R_ * 2)         // ushort region, VC_*E_ ushorts (49.2 MB)
#define AL_OFF   (AH_OFF + (size_t)VC_ * E_ / 2)     // ushort region, VC_*E_ ushorts

#define NEG_INF (-3.4e38f)

typedef __bf16 bf16x8 __attribute__((ext_vector_type(8)));
typedef unsigned short u16x8 __attribute__((ext_vector_type(8)));
typedef float  f32x4  __attribute__((ext_vector_type(4)));

// global -> LDS direct copy, 16B per lane. LDS dest = wave-uniform base + lane*16.
__device__ __forceinline__ void async_ld16(const void* gptr, void* lptr) {
    __builtin_amdgcn_global_load_lds(
        (const __attribute__((address_space(1))) void*)(uintptr_t)gptr,
        (__attribute__((address_space(3))) void*)(unsigned)(uintptr_t)lptr,
        16, 0, 0);
}

__device__ __forceinline__ bool better(float v, int i, float bv, int bi) {
    return (v > bv) || (v == bv && i < bi);
}

__device__ __forceinline__ float bfpair(unsigned short h, unsigned short l) {
    return __uint_as_float((unsigned)h << 16) + __uint_as_float((unsigned)l << 16);
}

// ---------------------------------------------------------------------------
// Kernel S0a: split we (fp32 [D,E]) into bf16 hi/lo AND zero wsq (fused).
// Grid 768 blocks; blocks 0..124 also zero the 32000-entry wsq accumulator.
// ---------------------------------------------------------------------------
__global__ __launch_bounds__(256) void k_prep_we(const float* __restrict__ x,
                                                 unsigned short* __restrict__ hi,
                                                 unsigned short* __restrict__ lo,
                                                 float* __restrict__ wsq) {
    int gi = blockIdx.x * 256 + threadIdx.x;
    if (gi < VC_) wsq[gi] = 0.f;
    int i = gi * 4;
    float4 v = *(const float4*)(x + i);
    ushort4 h, l;
    __bf16 b;
    b = (__bf16)v.x; h.x = __builtin_bit_cast(unsigned short, b); l.x = __builtin_bit_cast(unsigned short, (__bf16)(v.x - (float)b));
    b = (__bf16)v.y; h.y = __builtin_bit_cast(unsigned short, b); l.y = __builtin_bit_cast(unsigned short, (__bf16)(v.y - (float)b));
    b = (__bf16)v.z; h.z = __builtin_bit_cast(unsigned short, b); l.z = __builtin_bit_cast(unsigned short, (__bf16)(v.z - (float)b));
    b = (__bf16)v.w; h.w = __builtin_bit_cast(unsigned short, b); l.w = __builtin_bit_cast(unsigned short, (__bf16)(v.w - (float)b));
    *(ushort4*)(hi + i) = h;
    *(ushort4*)(lo + i) = l;
}

// ---------------------------------------------------------------------------
// Kernel S0b: split fp32 array into bf16 hi/lo (few [VC,E], 24000 blocks).
// ---------------------------------------------------------------------------
__global__ __launch_bounds__(256) void k_split(const float* __restrict__ x,
                                               unsigned short* __restrict__ hi,
                                               unsigned short* __restrict__ lo) {
    int i = (blockIdx.x * 256 + threadIdx.x) * 4;   // grid sized exactly
    float4 v = *(const float4*)(x + i);
    ushort4 h, l;
    __bf16 b;
    b = (__bf16)v.x; h.x = __builtin_bit_cast(unsigned short, b); l.x = __builtin_bit_cast(unsigned short, (__bf16)(v.x - (float)b));
    b = (__bf16)v.y; h.y = __builtin_bit_cast(unsigned short, b); l.y = __builtin_bit_cast(unsigned short, (__bf16)(v.y - (float)b));
    b = (__bf16)v.z; h.z = __builtin_bit_cast(unsigned short, b); l.z = __builtin_bit_cast(unsigned short, (__bf16)(v.z - (float)b));
    b = (__bf16)v.w; h.w = __builtin_bit_cast(unsigned short, b); l.w = __builtin_bit_cast(unsigned short, (__bf16)(v.w - (float)b));
    *(ushort4*)(hi + i) = h;
    *(ushort4*)(lo + i) = l;
}

// ---------------------------------------------------------------------------
// Kernel A: s[r,d] = sum_np P[r,np,d]; sb = bf16(s); invp[r] = 1/||P_r||;
// FUSED: also copies P rows into Z[r, 2:6, :] (P is already in registers).
// ---------------------------------------------------------------------------
__global__ __launch_bounds__(256) void k_sum_pnorm(const float* __restrict__ P,
                                                   float* __restrict__ s,
                                                   unsigned short* __restrict__ sb,
                                                   float* __restrict__ invp,
                                                   float* __restrict__ outZ) {
    int r = blockIdx.x;
    int t = threadIdx.x;
    const float* base = P + (size_t)r * NP_ * D_;
    float4 acc = make_float4(0.f, 0.f, 0.f, 0.f);
    float sq = 0.f;
#pragma unroll
    for (int np = 0; np < NP_; ++np) {
        float4 v = *(const float4*)(base + (size_t)np * D_ + t * 4);
        acc.x += v.x; acc.y += v.y; acc.z += v.z; acc.w += v.w;
        sq += v.x * v.x + v.y * v.y + v.z * v.z + v.w * v.w;
        *(float4*)(outZ + ((size_t)r * 6 + KTOP + np) * D_ + t * 4) = v;  // Z[r,2+np,:]
    }
    *(float4*)(s + (size_t)r * D_ + t * 4) = acc;
    ushort4 o;
    __bf16 b;
    b = (__bf16)acc.x; o.x = __builtin_bit_cast(unsigned short, b);
    b = (__bf16)acc.y; o.y = __builtin_bit_cast(unsigned short, b);
    b = (__bf16)acc.z; o.z = __builtin_bit_cast(unsigned short, b);
    b = (__bf16)acc.w; o.w = __builtin_bit_cast(unsigned short, b);
    *(ushort4*)(sb + (size_t)r * D_ + t * 4) = o;

    __shared__ float red[256];
    red[t] = sq;
    __syncthreads();
    for (int off = 128; off > 0; off >>= 1) {
        if (t < off) red[t] += red[t + off];
        __syncthreads();
    }
    if (t == 0) invp[r] = 1.0f / fmaxf(sqrtf(red[0]), EPS_);
}

// ---------------------------------------------------------------------------
// Kernel B: split-bf16 MFMA GEMM — 256(v) x 128(d) tile, 8 waves (512 thr),
// BK=32, 3-buffer circular LDS pipeline, depth-2 prefetch, vmcnt(12).
//   T[v,d] = dot(few[v,:], we[d,:]) + bias[v]  via  Ah*Bh + Al*Bh + Ah*Bl
// Epilogue v2: T stored as bf16 hi/lo PAIR (Th=Tb, Tl) — halves write traffic
// vs fp32+bf16 (201 -> 136 MB). Consumers reconstruct float(Th)+float(Tl)
// (error ~|T|*2^-17). Row-sumsq (exact fp32 val) -> wsq atomics unchanged.
// ---------------------------------------------------------------------------
__global__ __launch_bounds__(512) void k_gemm_T_mfma(const unsigned short* __restrict__ Ahg, // few hi [VC,E]
                                                     const unsigned short* __restrict__ Alg, // few lo [VC,E]
                                                     const unsigned short* __restrict__ Bhg, // weh [D,E]
                                                     const unsigned short* __restrict__ Blg, // wel [D,E]
                                                     const float* __restrict__ bias,
                                                     unsigned short* __restrict__ Th,
                                                     unsigned short* __restrict__ Tl,
                                                     float* __restrict__ wsq) {
    __shared__ __align__(16) unsigned short Ash[3][256 * 32];  // 3 x 16 KB
    __shared__ __align__(16) unsigned short Asl[3][256 * 32];  // 3 x 16 KB
    __shared__ __align__(16) unsigned short Bsh[3][128 * 32];  // 3 x  8 KB
    __shared__ __align__(16) unsigned short Bsl[3][128 * 32];  // 3 x  8 KB

    int tid = threadIdx.x;
    int wid = tid >> 6, lane = tid & 63;
    int quad = lane >> 4, l15 = lane & 15;
    int wm = wid >> 1, wn = wid & 1;       // 4 x 2 wave grid
    // Bijective XCD swizzle: nwg=1000, 125/XCD-chunk, v-major.
    int id  = blockIdx.x;
    int swz = (id & 7) * 125 + (id >> 3);
    int v0 = (swz >> 3) * 256;     // 125 v-panels
    int d0 = (swz & 7) * 128;      // 8 d-blocks per panel

    f32x4 acc[4][4];
#pragma unroll
    for (int i = 0; i < 4; ++i)
#pragma unroll
        for (int j = 0; j < 4; ++j) acc[i][j] = f32x4{0.f, 0.f, 0.f, 0.f};

    int r_lane = lane >> 2;            // staging row within 16-row group
    int slot   = lane & 3;             // physical 16B slot this lane writes

    // LDS physical (row, p) holds logical slot (p - (row>>1))&3 (bank
    // de-conflict); staged by pre-rotating the global source column.
#define STAGE_T(buf, kk)                                                           \
    {                                                                              \
_Pragma("unroll")                                                                  \
        for (int j = 0; j < 2; ++j) {                                              \
            int rowt = j * 128 + wid * 16 + r_lane;                                \
            int ss = (slot - (rowt >> 1)) & 3;                                     \
            async_ld16(Ahg + (size_t)(v0 + rowt) * E_ + (kk) + ss * 8,             \
                       (void*)(Ash[buf] + (j * 128 + wid * 16) * 32));             \
            async_ld16(Alg + (size_t)(v0 + rowt) * E_ + (kk) + ss * 8,             \
                       (void*)(Asl[buf] + (j * 128 + wid * 16) * 32));             \
        }                                                                          \
        {                                                                          \
            int rowb = wid * 16 + r_lane;                                          \
            int ssb = (slot - (rowb >> 1)) & 3;                                    \
            async_ld16(Bhg + (size_t)(d0 + rowb) * E_ + (kk) + ssb * 8,            \
                       (void*)(Bsh[buf] + (wid * 16) * 32));                       \
            async_ld16(Blg + (size_t)(d0 + rowb) * E_ + (kk) + ssb * 8,            \
                       (void*)(Bsl[buf] + (wid * 16) * 32));                       \
        }                                                                          \
    }

    // Prologue: 2 tiles in flight (12 loads/thread)
    STAGE_T(0, 0);
    STAGE_T(1, 32);

    const int NT = E_ / 32;            // 24 K-tiles
    int cur = 0;
    for (int kt = 0; kt < NT; ++kt) {
        int kn = (kt + 2 < NT) ? (kt + 2) * 32 : kt * 32;  // dummy tail re-stage
        int nb = cur + 2; if (nb >= 3) nb -= 3;
        STAGE_T(nb, kn);               // 6 more loads -> <=18 outstanding

        asm volatile("s_waitcnt vmcnt(12)" ::: "memory");   // tile kt landed
        __builtin_amdgcn_s_barrier();                       // buf[cur] ready
        asm volatile("" ::: "memory");

        bf16x8 fbh[4], fbl[4];
#pragma unroll
        for (int nt = 0; nt < 4; ++nt) {
            int row = wn * 64 + nt * 16 + l15;
            int ps = (quad + (row >> 1)) & 3;
            int off = row * 32 + ps * 8;
            fbh[nt] = *(const bf16x8*)(Bsh[cur] + off);
            fbl[nt] = *(const bf16x8*)(Bsl[cur] + off);
        }
        __builtin_amdgcn_s_setprio(1);
#pragma unroll
        for (int mt = 0; mt < 4; ++mt) {
            int row = wm * 64 + mt * 16 + l15;
            int ps = (quad + (row >> 1)) & 3;
            int off = row * 32 + ps * 8;
            bf16x8 fah = *(const bf16x8*)(Ash[cur] + off);
            bf16x8 fal = *(const bf16x8*)(Asl[cur] + off);
#pragma unroll
            for (int nt = 0; nt < 4; ++nt) {
                acc[mt][nt] = __builtin_amdgcn_mfma_f32_16x16x32_bf16(fah, fbh[nt], acc[mt][nt], 0, 0, 0);
                acc[mt][nt] = __builtin_amdgcn_mfma_f32_16x16x32_bf16(fal, fbh[nt], acc[mt][nt], 0, 0, 0);
                acc[mt][nt] = __builtin_amdgcn_mfma_f32_16x16x32_bf16(fah, fbl[nt], acc[mt][nt], 0, 0, 0);
            }
        }
        __builtin_amdgcn_s_setprio(0);

        __builtin_amdgcn_sched_barrier(0);   // keep reads+MFMA before barrier#2
        __builtin_amdgcn_s_barrier();        // all waves done reading buf[cur]
        asm volatile("" ::: "memory");
        cur = (cur == 2) ? 0 : cur + 1;
    }
#undef STAGE_T

    // Epilogue: Th/Tl bf16 pair, row-sumsq partials -> wsq atomics
    float sq[4][4] = {};
#pragma unroll
    for (int mt = 0; mt < 4; ++mt) {
        int vbase = v0 + wm * 64 + mt * 16 + quad * 4;
        float bv[4];
#pragma unroll
        for (int rg = 0; rg < 4; ++rg) bv[rg] = bias[vbase + rg];
#pragma unroll
        for (int nt = 0; nt < 4; ++nt) {
            int d = d0 + wn * 64 + nt * 16 + l15;
#pragma unroll
            for (int rg = 0; rg < 4; ++rg) {
                float val = acc[mt][nt][rg] + bv[rg];
                __bf16 hb = (__bf16)val;
                __bf16 lb = (__bf16)(val - (float)hb);
                Th[(size_t)(vbase + rg) * D_ + d] = __builtin_bit_cast(unsigned short, hb);
                Tl[(size_t)(vbase + rg) * D_ + d] = __builtin_bit_cast(unsigned short, lb);
                sq[mt][rg] += val * val;
            }
        }
    }
#pragma unroll
    for (int mt = 0; mt < 4; ++mt)
#pragma unroll
        for (int rg = 0; rg < 4; ++rg) {
            float p = sq[mt][rg];
            p += __shfl_xor(p, 1); p += __shfl_xor(p, 2);
            p += __shfl_xor(p, 4); p += __shfl_xor(p, 8);
            if (l15 == 0) atomicAdd(&wsq[v0 + wm * 64 + mt * 16 + quad * 4 + rg], p);
        }
}

// ---------------------------------------------------------------------------
// Kernel W: invw[v] = 1 / max(2*sqrt(wsq[v]), eps)
// ---------------------------------------------------------------------------
__global__ __launch_bounds__(256) void k_invw(const float* __restrict__ wsq,
                                              float* __restrict__ invw) {
    int v = blockIdx.x * 256 + threadIdx.x;
    if (v < VC_) invw[v] = 1.0f / fmaxf(2.0f * sqrtf(wsq[v]), EPS_);
}

// ---------------------------------------------------------------------------
// Kernel C: bf16 MFMA candidate GEMM — 256x256 tile, 8 waves (512 thr),
// BK=32, 4-buffer circular LDS pipeline, depth-3 prefetch, vmcnt(12).
// (Byte-identical to R6 form — measured 193.7 µs there, 228.6 in R7 with the
// same code: re-measuring to resolve the cross-round variance question.)
// ---------------------------------------------------------------------------
__global__ __launch_bounds__(512) void k_scores_mfma(const unsigned short* __restrict__ Tb,
                                                     const unsigned short* __restrict__ sb,
                                                     const float* __restrict__ invw,
                                                     float* __restrict__ pval,
                                                     int* __restrict__ pidx) {
    __shared__ __align__(16) unsigned short As[4][256 * 32];  // 4 x 16 KB  [v-row][k]
    __shared__ __align__(16) unsigned short Bs[4][256 * 32];  // 4 x 16 KB  [r-row][k]

    int tid = threadIdx.x;
    int wid = tid >> 6, lane = tid & 63;
    int quad = lane >> 4, l15 = lane & 15;
    int wm = wid >> 2, wn = wid & 3;       // 2 x 4 wave grid
    // T1: nwg=1000, 125/XCD-chunk, v-major (8 r-blocks of a panel on one XCD).
    int id   = blockIdx.x;
    int swz  = (id & 7) * 125 + (id >> 3);
    int vblk = swz >> 3;               // 0..124  (256-v panel)
    int rblk = swz & 7;                // 0..7    (256-r block)
    int v0 = vblk * 256;
    int r0 = rblk * 256;

    f32x4 acc[8][4];
#pragma unroll
    for (int i = 0; i < 8; ++i)
#pragma unroll
        for (int j = 0; j < 4; ++j) acc[i][j] = f32x4{0.f, 0.f, 0.f, 0.f};

    int r_lane = lane >> 2;            // staging row within 16-row group
    int slot   = lane & 3;             // physical 16B slot this lane writes

    // LDS physical (row, p) holds logical slot (p - (row>>1))&3 (bank
    // de-conflict); staged by pre-rotating the global source column.
#define STAGE_SC(buf, kk)                                                          \
    {                                                                              \
_Pragma("unroll")                                                                  \
        for (int j = 0; j < 2; ++j) {                                              \
            int rowt = j * 128 + wid * 16 + r_lane;                                \
            int ss = (slot - (rowt >> 1)) & 3;                                     \
            async_ld16(Tb + (size_t)(v0 + rowt) * D_ + (kk) + ss * 8,              \
                       (void*)(As[buf] + (j * 128 + wid * 16) * 32));              \
            async_ld16(sb + (size_t)(r0 + rowt) * D_ + (kk) + ss * 8,              \
                       (void*)(Bs[buf] + (j * 128 + wid * 16) * 32));              \
        }                                                                          \
    }

    // Prologue: 3 tiles in flight (12 loads/thread)
    STAGE_SC(0, 0);
    STAGE_SC(1, 32);
    STAGE_SC(2, 64);

    const int NT = D_ / 32;            // 32 K-tiles
    for (int kt = 0; kt < NT; ++kt) {
        int cur = kt & 3;
        int kn  = (kt + 3 < NT) ? (kt + 3) * 32 : kt * 32;  // dummy tail re-stage
        STAGE_SC((kt + 3) & 3, kn);    // 4 more loads -> <=16 outstanding

        asm volatile("s_waitcnt vmcnt(12)" ::: "memory");   // tile kt landed
        __builtin_amdgcn_s_barrier();                       // buf[cur] ready
        asm volatile("" ::: "memory");

        bf16x8 bfr[4];
#pragma unroll
        for (int nt = 0; nt < 4; ++nt) {
            int row = wn * 64 + nt * 16 + l15;
            int ps = (quad + (row >> 1)) & 3;
            bfr[nt] = *(const bf16x8*)(Bs[cur] + row * 32 + ps * 8);
        }
        __builtin_amdgcn_s_setprio(1);
#pragma unroll
        for (int mt = 0; mt < 8; ++mt) {
            int row = wm * 128 + mt * 16 + l15;
            int ps = (quad + (row >> 1)) & 3;
            bf16x8 af = *(const bf16x8*)(As[cur] + row * 32 + ps * 8);
#pragma unroll
            for (int nt = 0; nt < 4; ++nt)
                acc[mt][nt] = __builtin_amdgcn_mfma_f32_16x16x32_bf16(af, bfr[nt], acc[mt][nt], 0, 0, 0);
        }
        __builtin_amdgcn_s_setprio(0);

        __builtin_amdgcn_sched_barrier(0);   // keep reads+MFMA before barrier#2
        __builtin_amdgcn_s_barrier();        // all waves done reading buf[cur]
        asm volatile("" ::: "memory");
    }
#undef STAGE_SC

    // Epilogue: scale by invw[v]; per r, top-2 over this wave's 128 v's.
    // Each (wm) half-panel is its own partial block (NCB=250 layout kept).
    float iw[8][4];
#pragma unroll
    for (int mt = 0; mt < 8; ++mt)
#pragma unroll
        for (int rg = 0; rg < 4; ++rg)
            iw[mt][rg] = invw[v0 + wm * 128 + mt * 16 + quad * 4 + rg];

#pragma unroll
    for (int nt = 0; nt < 4; ++nt) {
        float b1 = NEG_INF, b2 = NEG_INF;
        int i1 = 0x7fffffff, i2 = 0x7fffffff;
#pragma unroll
        for (int mt = 0; mt < 8; ++mt)
#pragma unroll
            for (int rg = 0; rg < 4; ++rg) {
                float val = acc[mt][nt][rg] * iw[mt][rg];
                int v = v0 + wm * 128 + mt * 16 + quad * 4 + rg;
                if (better(val, v, b1, i1)) { b2 = b1; i2 = i1; b1 = val; i1 = v; }
                else if (better(val, v, b2, i2)) { b2 = val; i2 = v; }
            }
#pragma unroll
        for (int off = 16; off <= 32; off <<= 1) {
            float o1 = __shfl_xor(b1, off), o2 = __shfl_xor(b2, off);
            int  oi1 = __shfl_xor(i1, off), oi2 = __shfl_xor(i2, off);
            if (better(o1, oi1, b1, i1)) {
                if (better(b1, i1, o2, oi2)) { b2 = b1; i2 = i1; } else { b2 = o2; i2 = oi2; }
                b1 = o1; i1 = oi1;
            } else if (better(o1, oi1, b2, i2)) { b2 = o1; i2 = oi1; }
        }
        if (quad == 0) {
            int rl = wn * 64 + nt * 16 + l15;
            size_t off = ((size_t)(r0 + rl) * NCB + vblk * 2 + wm) * 2;
            pval[off] = b1;     pidx[off] = i1;
            pval[off + 1] = b2; pidx[off + 1] = i2;
        }
    }
}

// ---------------------------------------------------------------------------
// Kernel D: top-8 candidates per row from the 500 partials (approx ranking)
// ---------------------------------------------------------------------------
__global__ __launch_bounds__(256) void k_topk8(const float* __restrict__ pval,
                                               const int* __restrict__ pidx,
                                               int* __restrict__ cands) {
    int r = blockIdx.x, t = threadIdx.x;
    __shared__ float v[512];
    __shared__ int  id[512];
    for (int c = t; c < 512; c += 256) {
        if (c < NCB * 2) { v[c] = pval[(size_t)r * NCB * 2 + c]; id[c] = pidx[(size_t)r * NCB * 2 + c]; }
        else             { v[c] = NEG_INF; id[c] = 0x7fffffff; }
    }
    __syncthreads();
    if (t == 0) {
        float bv[NCAND]; int bi[NCAND];
#pragma unroll
        for (int j = 0; j < NCAND; ++j) { bv[j] = NEG_INF; bi[j] = 0x7fffffff; }
        for (int c = 0; c < NCB * 2; ++c) {
            float x = v[c]; int xi = id[c];
            if (better(x, xi, bv[NCAND - 1], bi[NCAND - 1])) {
                int j = NCAND - 1;
                while (j > 0 && better(x, xi, bv[j - 1], bi[j - 1])) {
                    bv[j] = bv[j - 1]; bi[j] = bi[j - 1]; --j;
                }
                bv[j] = x; bi[j] = xi;
            }
        }
#pragma unroll
        for (int j = 0; j < NCAND; ++j) cands[r * NCAND + j] = bi[j];
    }
}

// ---------------------------------------------------------------------------
// Kernel E: exact rescore of 8 candidates/row -> final top-2 + values.
// T reconstructed from bf16 hi/lo pair: float(Th)+float(Tl) (~1e-7 error).
// ---------------------------------------------------------------------------
__global__ __launch_bounds__(256) void k_rescore(const float* __restrict__ s,
                                                 const unsigned short* __restrict__ Th,
                                                 const unsigned short* __restrict__ Tl,
                                                 const int* __restrict__ cands,
                                                 const float* __restrict__ invw,
                                                 const float* __restrict__ invp,
                                                 float* __restrict__ outv,
                                                 int* __restrict__ tidx) {
    int r = blockIdx.x, t = threadIdx.x;
    int cg = t >> 5, l32 = t & 31;          // 8 groups of 32 lanes
    int c = cands[r * NCAND + cg];
    const unsigned short* hrow = Th + (size_t)c * D_;
    const unsigned short* lrow = Tl + (size_t)c * D_;
    const float* srow = s + (size_t)r * D_;
    float p = 0.f;
#pragma unroll
    for (int j = 0; j < 8; ++j) {
        int e = (j * 32 + l32) * 4;
        float4 a = *(const float4*)(srow + e);
        ushort4 h = *(const ushort4*)(hrow + e);
        ushort4 l = *(const ushort4*)(lrow + e);
        p += a.x * bfpair(h.x, l.x) + a.y * bfpair(h.y, l.y)
           + a.z * bfpair(h.z, l.z) + a.w * bfpair(h.w, l.w);
    }
#pragma unroll
    for (int off = 16; off >= 1; off >>= 1) p += __shfl_xor(p, off);  // stays in 32-group
    __shared__ float sc[NCAND];
    if (l32 == 0) sc[cg] = p;
    __syncthreads();
    if (t == 0) {
        float ip = invp[r];
        float b1 = NEG_INF, b2 = NEG_INF;
        int i1 = 0x7fffffff, i2 = 0x7fffffff;
#pragma unroll
        for (int j = 0; j < NCAND; ++j) {
            int ci = cands[r * NCAND + j];
            float val = sc[j] * invw[ci] * ip;
            if (better(val, ci, b1, i1)) { b2 = b1; i2 = i1; b1 = val; i1 = ci; }
            else if (better(val, ci, b2, i2)) { b2 = val; i2 = ci; }
        }
        outv[(size_t)r * 2 + 0] = b1;
        outv[(size_t)r * 2 + 1] = b2;
        tidx[r * 2 + 0] = i1;
        tidx[r * 2 + 1] = i2;
    }
}

// ---------------------------------------------------------------------------
// Kernel F: Z[r, 0:2, :] = T[idx] (reconstructed from Th/Tl).
// (P rows already copied by k_sum_pnorm.)  Grid: R_*2 blocks.
// ---------------------------------------------------------------------------
__global__ __launch_bounds__(256) void k_writeZ(const unsigned short* __restrict__ Th,
                                                const unsigned short* __restrict__ Tl,
                                                const int* __restrict__ tidx,
                                                float* __restrict__ out) {
    int blk = blockIdx.x;  // r*2 + j
    int r = blk >> 1, j = blk & 1;
    size_t c = (size_t)tidx[r * 2 + j] * D_;
    int e = threadIdx.x * 4;
    ushort4 h = *(const ushort4*)(Th + c + e);
    ushort4 l = *(const ushort4*)(Tl + c + e);
    float4 v;
    v.x = bfpair(h.x, l.x); v.y = bfpair(h.y, l.y);
    v.z = bfpair(h.z, l.z); v.w = bfpair(h.w, l.w);
    *(float4*)(out + ((size_t)r * 6 + j) * D_ + e) = v;
}

// ---------------------------------------------------------------------------
extern "C" void kernel_launch(void* const* d_in, const int* in_sizes, int n_in,
                              void* d_out, int out_size, void* d_ws, size_t ws_size,
                              hipStream_t stream) {
    const float* P   = (const float*)d_in[0];  // [32,64,4,1024]
    const float* we  = (const float*)d_in[1];  // [1024,768]
    const float* few = (const float*)d_in[2];  // [32000,768]
    const float* feb = (const float*)d_in[3];  // [32000]
    float* out = (float*)d_out;                // Z (12,582,912) then values (4096)
    float* ws  = (float*)d_ws;

    float* s    = ws + S_OFF;
    float* invw = ws + INVW_OFF;
    float* invp = ws + INVP_OFF;
    float* wsq  = ws + WSQ_OFF;
    float* pval = ws + PV_OFF;
    int*   pidx = (int*)(ws + PI_OFF);
    unsigned short* sb  = (unsigned short*)(ws + SB_OFF);
    unsigned short* Th  = (unsigned short*)(ws + TB_OFF);
    unsigned short* Tl  = (unsigned short*)(ws + TL_OFF);
    unsigned short* weh = (unsigned short*)(ws + WH_OFF);
    unsigned short* wel = (unsigned short*)(ws + WL_OFF);
    int*   cands = (int*)(ws + CAND_OFF);
    int*   tidx  = (int*)(ws + TIDX_OFF);
    unsigned short* fewh = (unsigned short*)(ws + AH_OFF);
    unsigned short* fewl = (unsigned short*)(ws + AL_OFF);
    float* outv = out + (size_t)R_ * 6 * D_;

    k_prep_we<<<(D_ * E_) / 1024, 256, 0, stream>>>(we, weh, wel, wsq);
    k_split<<<((size_t)VC_ * E_) / 1024, 256, 0, stream>>>(few, fewh, fewl);
    k_sum_pnorm<<<R_, 256, 0, stream>>>(P, s, sb, invp, out);
    k_gemm_T_mfma<<<1000, 512, 0, stream>>>(fewh, fewl, weh, wel, feb, Th, Tl, wsq);
    k_invw<<<(VC_ + 255) / 256, 256, 0, stream>>>(wsq, invw);
    k_scores_mfma<<<1000, 512, 0, stream>>>(Th, sb, invw, pval, pidx);
    k_topk8<<<R_, 256, 0, stream>>>(pval, pidx, cands);
    k_rescore<<<R_, 256, 0, stream>>>(s, Th, Tl, cands, invw, invp, outv, tidx);
    k_writeZ<<<R_ * 2, 256, 0, stream>>>(Th, Tl, tidx, out);
}